// Round 1
// baseline (100.796 us; speedup 1.0000x reference)
//
#include <hip/hip_runtime.h>
#include <math.h>

typedef _Float16 h16;
typedef _Float16 h8 __attribute__((ext_vector_type(8)));
typedef float f32x4 __attribute__((ext_vector_type(4)));

__device__ inline void gl2lds16(const void* g, void* l) {
  __builtin_amdgcn_global_load_lds(
      (const __attribute__((address_space(1))) void*)g,
      (__attribute__((address_space(3))) void*)l, 16, 0, 0);
}

// ---------------- fp32 -> fp16 conversion ----------------
__global__ __launch_bounds__(256) void f2h(const float* __restrict__ in,
                                           h16* __restrict__ out, int n) {
  int i = (blockIdx.x * 256 + threadIdx.x) * 8;
  if (i >= n) return;
  float4 a = *(const float4*)(in + i);
  float4 b = *(const float4*)(in + i + 4);
  h8 o;
  o[0] = (h16)a.x; o[1] = (h16)a.y; o[2] = (h16)a.z; o[3] = (h16)a.w;
  o[4] = (h16)b.x; o[5] = (h16)b.y; o[6] = (h16)b.z; o[7] = (h16)b.w;
  *(h8*)(out + i) = o;
}

// ---------------- GEMM: C[r][c] = sum_k A[r][k] * Bw[c][k] + bias ----------------
// MODE 0: QKV fused (N=3072). Writes q/k/v fp16 as [B,H,S,D], bias from b0/b1/b2.
// MODE 1: final projection. Writes fp32 Cf row-major M x N, bias b0.
template <int MODE>
__global__ __launch_bounds__(256) void gemm_bt(
    const h16* __restrict__ A, const h16* __restrict__ Bw,
    const float* __restrict__ b0, const float* __restrict__ b1,
    const float* __restrict__ b2,
    h16* __restrict__ qo, h16* __restrict__ ko, h16* __restrict__ vo,
    float* __restrict__ Cf, int M, int N, int K) {
  __shared__ __align__(16) h16 Ash[128 * 32];
  __shared__ __align__(16) h16 Bsh[128 * 32];
  const int tid = threadIdx.x;
  const int wave = tid >> 6, lane = tid & 63;
  const int lr = lane & 15, lg = lane >> 4;
  const int wr = wave >> 1, wc = wave & 1;
  const int row0 = blockIdx.x * 128, col0 = blockIdx.y * 128;

  f32x4 acc[4][4] = {};

  const int nk = K >> 5;
  for (int kt = 0; kt < nk; ++kt) {
#pragma unroll
    for (int i = 0; i < 2; ++i) {
      const int grp = wave * 2 + i;
      const int c = grp * 64 + lane;
      const int r = c >> 2, cc = c & 3;
      gl2lds16(A + (size_t)(row0 + r) * K + kt * 32 + cc * 8, &Ash[grp * 512]);
      gl2lds16(Bw + (size_t)(col0 + r) * K + kt * 32 + cc * 8, &Bsh[grp * 512]);
    }
    __syncthreads();
    h8 af[4], bf[4];
#pragma unroll
    for (int m = 0; m < 4; ++m)
      af[m] = *(const h8*)&Ash[(wr * 64 + m * 16 + lr) * 32 + lg * 8];
#pragma unroll
    for (int n = 0; n < 4; ++n)
      bf[n] = *(const h8*)&Bsh[(wc * 64 + n * 16 + lr) * 32 + lg * 8];
#pragma unroll
    for (int m = 0; m < 4; ++m)
#pragma unroll
      for (int n = 0; n < 4; ++n)
        acc[m][n] =
            __builtin_amdgcn_mfma_f32_16x16x32_f16(af[m], bf[n], acc[m][n], 0, 0, 0);
    __syncthreads();
  }

  // epilogue — each 128-wide column block lies entirely within one of q/k/v
  const int tsel = col0 >> 10;
  const float* bp = (MODE == 0) ? (tsel == 0 ? b0 : (tsel == 1 ? b1 : b2)) : b0;
  h16* outp = (MODE == 0) ? (tsel == 0 ? qo : (tsel == 1 ? ko : vo)) : nullptr;

#pragma unroll
  for (int m = 0; m < 4; ++m) {
#pragma unroll
    for (int n = 0; n < 4; ++n) {
#pragma unroll
      for (int j = 0; j < 4; ++j) {
        const int r = row0 + wr * 64 + m * 16 + lg * 4 + j;
        const int cidx = col0 + wc * 64 + n * 16 + lr;
        float val = acc[m][n][j];
        if (MODE == 0) {
          const int jj = cidx & 1023;
          val += bp[jj];
          const int hh = jj >> 6, dd = jj & 63;
          const int bb = r >> 11, ss = r & 2047;
          outp[(((size_t)bb * 16 + hh) * 2048 + ss) * 64 + dd] = (h16)val;
        } else {
          val += bp[cidx];
          Cf[(size_t)r * N + cidx] = val;
        }
      }
    }
  }
}

// ---------------- sliding-window attention ----------------
// grid: (S/64, B*H). One block handles 64 queries; their window union is
// exactly 128 keys [qb0-32, qb0+96). Out-of-range keys/values are staged as
// ZEROS (score 0 participates in softmax — matches reference zero-padding).
// Out-of-window slots (|t-s|>32) are masked to -inf.
__global__ __launch_bounds__(256) void swattn(const h16* __restrict__ Q,
                                              const h16* __restrict__ K,
                                              const h16* __restrict__ V,
                                              h16* __restrict__ O) {
  __shared__ __align__(16) h16 Ksh[128 * 72];      // [key][d], padded stride
  __shared__ __align__(16) h16 Vsh[64 * 136];      // transposed: [d][key]
  __shared__ __align__(16) h16 Psh[4][16 * 136];   // per-wave P, padded stride

  const int qb0 = blockIdx.x * 64;
  const int bh = blockIdx.y;
  const int b = bh >> 4, h = bh & 15;
  const int tid = threadIdx.x;
  const int wave = tid >> 6, lane = tid & 63;
  const int lr = lane & 15, lg = lane >> 4;

  const h16* Qb = Q + (size_t)bh * 2048 * 64;
  const h16* Kb = K + (size_t)bh * 2048 * 64;
  const h16* Vb = V + (size_t)bh * 2048 * 64;

  // stage K and V (V transposed), zero-filled outside [0, S)
#pragma unroll
  for (int i = 0; i < 4; ++i) {
    const int c = tid * 4 + i;       // 1024 chunks of 8 halves
    const int row = c >> 3, c8 = c & 7;
    const int t = qb0 - 32 + row;
    h8 kv, vv;
    if (t >= 0 && t < 2048) {
      kv = *(const h8*)&Kb[(size_t)t * 64 + c8 * 8];
      vv = *(const h8*)&Vb[(size_t)t * 64 + c8 * 8];
    } else {
#pragma unroll
      for (int j = 0; j < 8; ++j) { kv[j] = (h16)0.f; vv[j] = (h16)0.f; }
    }
    *(h8*)&Ksh[row * 72 + c8 * 8] = kv;
#pragma unroll
    for (int j = 0; j < 8; ++j) Vsh[(c8 * 8 + j) * 136 + row] = vv[j];
  }
  __syncthreads();

  // Q fragments straight from global (row-major, D=64 contiguous)
  const int qrow = qb0 + wave * 16 + lr;
  h8 qa[2];
#pragma unroll
  for (int kk = 0; kk < 2; ++kk)
    qa[kk] = *(const h8*)&Qb[(size_t)qrow * 64 + kk * 32 + lg * 8];

  // scores: this wave's 16 queries x 128 keys
  f32x4 sacc[8] = {};
#pragma unroll
  for (int n = 0; n < 8; ++n)
#pragma unroll
    for (int kk = 0; kk < 2; ++kk) {
      h8 kb = *(const h8*)&Ksh[(n * 16 + lr) * 72 + kk * 32 + lg * 8];
      sacc[n] = __builtin_amdgcn_mfma_f32_16x16x32_f16(qa[kk], kb, sacc[n], 0, 0, 0);
    }

  // wave-parallel softmax in fp32. Lane layout: col = lr + 16n, row = lg*4+j.
  float p[8][4];
#pragma unroll
  for (int j = 0; j < 4; ++j) {
    const int wrow = wave * 16 + lg * 4 + j;  // query index within the 64-block
    float mx = -1e30f;
#pragma unroll
    for (int n = 0; n < 8; ++n) {
      const int d = n * 16 + lr - wrow;  // key - query + 32 (window coord)
      float s = (d < 0 || d > 64) ? -1e30f : sacc[n][j] * 0.125f;
      p[n][j] = s;
      mx = fmaxf(mx, s);
    }
#pragma unroll
    for (int off = 1; off < 16; off <<= 1) mx = fmaxf(mx, __shfl_xor(mx, off, 64));
    float sum = 0.f;
#pragma unroll
    for (int n = 0; n < 8; ++n) {
      const float e = __expf(p[n][j] - mx);
      p[n][j] = e;
      sum += e;
    }
#pragma unroll
    for (int off = 1; off < 16; off <<= 1) sum += __shfl_xor(sum, off, 64);
    const float inv = 1.f / sum;
#pragma unroll
    for (int n = 0; n < 8; ++n) p[n][j] *= inv;
  }

  // P -> LDS (redistribute from C/D layout to A-operand layout)
#pragma unroll
  for (int n = 0; n < 8; ++n)
#pragma unroll
    for (int j = 0; j < 4; ++j)
      Psh[wave][(lg * 4 + j) * 136 + n * 16 + lr] = (h16)p[n][j];
  __syncthreads();

  // PV: (16 x 128) x (128 x 64)
  f32x4 oacc[4] = {};
#pragma unroll
  for (int kk = 0; kk < 4; ++kk) {
    h8 pa = *(const h8*)&Psh[wave][lr * 136 + kk * 32 + lg * 8];
#pragma unroll
    for (int n = 0; n < 4; ++n) {
      h8 vb = *(const h8*)&Vsh[(n * 16 + lr) * 136 + kk * 32 + lg * 8];
      oacc[n] = __builtin_amdgcn_mfma_f32_16x16x32_f16(pa, vb, oacc[n], 0, 0, 0);
    }
  }

  // write attn output token-major [B,S,E] for the final GEMM
#pragma unroll
  for (int n = 0; n < 4; ++n)
#pragma unroll
    for (int j = 0; j < 4; ++j) {
      const int s = qb0 + wave * 16 + lg * 4 + j;
      const int d = n * 16 + lr;
      O[((size_t)b * 2048 + s) * 1024 + h * 64 + d] = (h16)oacc[n][j];
    }
}

extern "C" void kernel_launch(void* const* d_in, const int* in_sizes, int n_in,
                              void* d_out, int out_size, void* d_ws, size_t ws_size,
                              hipStream_t stream) {
  const float* hs = (const float*)d_in[0];
  const float* qw = (const float*)d_in[1];
  const float* qb = (const float*)d_in[2];
  const float* kw = (const float*)d_in[3];
  const float* kb = (const float*)d_in[4];
  const float* vw = (const float*)d_in[5];
  const float* vb = (const float*)d_in[6];
  const float* ow = (const float*)d_in[7];
  const float* ob = (const float*)d_in[8];

  const int M = in_sizes[0] / 1024;  // B * S = 4096

  h16* hsH = (h16*)d_ws;
  h16* wqkv = hsH + (size_t)M * 1024;           // 3072 x 1024
  h16* woH = wqkv + (size_t)3072 * 1024;        // 1024 x 1024
  h16* qH = woH + (size_t)1024 * 1024;          // [B,H,S,D]
  h16* kH = qH + (size_t)M * 1024;
  h16* vH = kH + (size_t)M * 1024;
  h16* attnH = vH + (size_t)M * 1024;           // [B,S,E]

  f2h<<<(M * 1024 / 8 + 255) / 256, 256, 0, stream>>>(hs, hsH, M * 1024);
  f2h<<<512, 256, 0, stream>>>(qw, wqkv, 1024 * 1024);
  f2h<<<512, 256, 0, stream>>>(kw, wqkv + 1024 * 1024, 1024 * 1024);
  f2h<<<512, 256, 0, stream>>>(vw, wqkv + 2048 * 1024, 1024 * 1024);
  f2h<<<512, 256, 0, stream>>>(ow, woH, 1024 * 1024);

  gemm_bt<0><<<dim3(M / 128, 24), 256, 0, stream>>>(
      hsH, wqkv, qb, kb, vb, qH, kH, vH, nullptr, M, 3072, 1024);

  swattn<<<dim3(32, M / 2048 * 16), 256, 0, stream>>>(qH, kH, vH, attnH);

  gemm_bt<1><<<dim3(M / 128, 8), 256, 0, stream>>>(
      attnH, woH, ob, nullptr, nullptr, nullptr, nullptr, nullptr,
      (float*)d_out, M, 1024, 1024);
}

// Round 2
// 89.079 us; speedup vs baseline: 1.1315x; 1.1315x over previous
//
#include <hip/hip_runtime.h>
#include <math.h>

typedef _Float16 h16;
typedef _Float16 h8 __attribute__((ext_vector_type(8)));
typedef float f32x4 __attribute__((ext_vector_type(4)));

__device__ inline void gl2lds16(const void* g, void* l) {
  __builtin_amdgcn_global_load_lds(
      (const __attribute__((address_space(1))) void*)g,
      (__attribute__((address_space(3))) void*)l, 16, 0, 0);
}

__device__ inline void barrier_raw() {
  asm volatile("" ::: "memory");
  __builtin_amdgcn_s_barrier();
  asm volatile("" ::: "memory");
}

#define VMCNT(N) asm volatile("s_waitcnt vmcnt(" #N ")" ::: "memory")

// ---------------- fused fp32 -> fp16 conversion (hs + 4 weights) ----------------
// dst regions are laid out contiguously in d_ws: [hs | qw | kw | vw | ow]
__global__ __launch_bounds__(256) void f2h_all(
    const float* __restrict__ hs, const float* __restrict__ w0,
    const float* __restrict__ w1, const float* __restrict__ w2,
    const float* __restrict__ w3, h16* __restrict__ dst, int hsN) {
  int i = (blockIdx.x * 256 + threadIdx.x) * 8;
  const int tot = hsN + 4 * 1048576;
  if (i >= tot) return;
  const float* src;
  int off;
  if (i < hsN) {
    src = hs; off = i;
  } else {
    int k = i - hsN;
    int seg = k >> 20;
    off = k & 1048575;
    src = seg == 0 ? w0 : seg == 1 ? w1 : seg == 2 ? w2 : w3;
  }
  float4 a = *(const float4*)(src + off);
  float4 b = *(const float4*)(src + off + 4);
  h8 o;
  o[0] = (h16)a.x; o[1] = (h16)a.y; o[2] = (h16)a.z; o[3] = (h16)a.w;
  o[4] = (h16)b.x; o[5] = (h16)b.y; o[6] = (h16)b.z; o[7] = (h16)b.w;
  *(h8*)(dst + i) = o;
}

// ---------------- QKV GEMM: 256x256 tile, BK=64, 8-wave, counted-vmcnt pipeline ----
// C[r][c] = sum_k A[r][k] * Bw[c][k] + bias; scatter-writes q/k/v as [B,H,S,D] fp16.
// LDS swizzle: LDS[row][slot] holds global slot (slot ^ (row&7)); linear gl2lds dest,
// inverse-swizzled global source, swizzled ds_read (rule #21 both-sides).
__global__ __launch_bounds__(512, 2) void qkv8(
    const h16* __restrict__ A, const h16* __restrict__ Bw,
    const float* __restrict__ qb, const float* __restrict__ kb,
    const float* __restrict__ vb, h16* __restrict__ qo, h16* __restrict__ ko,
    h16* __restrict__ vo, int nbm, int cpx) {
  __shared__ __align__(16) h16 Asm[2][256][64];
  __shared__ __align__(16) h16 Bsm[2][256][64];

  const int tid = threadIdx.x;
  const int wid = tid >> 6, lane = tid & 63;
  const int lr = lane & 15, lg = lane >> 4;
  const int wr = wid >> 2, wc = wid & 3;   // wave tile: rows wr*128, cols wc*64
  const int srow = wid * 8 + (lane >> 3);  // staging row within a 64-row call
  const int lsrc = ((lane & 7) ^ (srow & 7)) * 8;  // inverse-swizzled source slot

  // XCD-aware bijective swizzle (nwg = nbm*12, divisible by 8)
  const int wg = (blockIdx.x % 8) * cpx + blockIdx.x / 8;
  const int bm = wg % nbm, bn = wg / nbm;
  const int row0 = bm * 256, col0 = bn * 256;

  const h16* Ag = A + (size_t)row0 * 1024;
  const h16* Bg = Bw + (size_t)col0 * 1024;

  auto stg = [&](const h16* g, h16* l, int rs) {
    gl2lds16(g + (size_t)(rs + srow) * 1024 + lsrc, l + (rs + wid * 8) * 64);
  };
  auto ldf = [&](const h16* base, int row, int kk) -> h8 {
    return *(const h8*)(base + row * 64 + ((kk * 4 + lg) ^ (lr & 7)) * 8);
  };

  f32x4 acc[8][4] = {};

  // prologue: stage tile 0 into buf0. B rows 0..255; A calls interleaved so the
  // 2 calls left in flight at each tile boundary are rows 64-127 / 192-255
  // (per-wave m-groups 2,3 — not read until phase 2).
  stg(Bg, &Bsm[0][0][0], 0);   stg(Bg, &Bsm[0][0][0], 64);
  stg(Bg, &Bsm[0][0][0], 128); stg(Bg, &Bsm[0][0][0], 192);
  stg(Ag, &Asm[0][0][0], 0);   stg(Ag, &Asm[0][0][0], 128);
  stg(Ag, &Asm[0][0][0], 64);  stg(Ag, &Asm[0][0][0], 192);
  VMCNT(2);
  barrier_raw();

  h8 bf[4][2], af[2][2];

#define MMA16(MG)                                                              \
  __builtin_amdgcn_s_setprio(1);                                               \
  _Pragma("unroll") for (int kk = 0; kk < 2; ++kk)                             \
      _Pragma("unroll") for (int mi = 0; mi < 2; ++mi)                         \
          _Pragma("unroll") for (int n = 0; n < 4; ++n)                        \
              acc[(MG)*2 + mi][n] = __builtin_amdgcn_mfma_f32_16x16x32_f16(    \
                  af[mi][kk], bf[n][kk], acc[(MG)*2 + mi][n], 0, 0, 0);        \
  __builtin_amdgcn_s_setprio(0)

  for (int t = 0; t < 16; ++t) {
    const int buf = t & 1;
    const h16* Ar = &Asm[buf][0][0];
    const h16* Br = &Bsm[buf][0][0];
    h16* Aw = &Asm[buf ^ 1][0][0];
    h16* Bww = &Bsm[buf ^ 1][0][0];
    const h16* Agt = Ag + (t + 1) * 64;
    const h16* Bgt = Bg + (t + 1) * 64;
    const bool st = (t < 15);

    // ---- phase 0: ds_read B all + A m0,1 ; stage B(t+1) rows 0-127 ----
#pragma unroll
    for (int n = 0; n < 4; ++n) {
      bf[n][0] = ldf(Br, wc * 64 + n * 16 + lr, 0);
      bf[n][1] = ldf(Br, wc * 64 + n * 16 + lr, 1);
    }
#pragma unroll
    for (int kk = 0; kk < 2; ++kk) {
      af[0][kk] = ldf(Ar, wr * 128 + 0 * 16 + lr, kk);
      af[1][kk] = ldf(Ar, wr * 128 + 1 * 16 + lr, kk);
    }
    if (st) { stg(Bgt, Bww, 0); stg(Bgt, Bww, 64); }
    barrier_raw();
    MMA16(0);
    barrier_raw();

    // ---- phase 1: A m2,3 ; stage B(t+1) rows 128-255 ; drain A mg2/3(t) ----
#pragma unroll
    for (int kk = 0; kk < 2; ++kk) {
      af[0][kk] = ldf(Ar, wr * 128 + 2 * 16 + lr, kk);
      af[1][kk] = ldf(Ar, wr * 128 + 3 * 16 + lr, kk);
    }
    if (st) { stg(Bgt, Bww, 128); stg(Bgt, Bww, 192); }
    barrier_raw();
    MMA16(1);
    if (st) { VMCNT(4); } else { VMCNT(0); }
    barrier_raw();

    // ---- phase 2: A m4,5 ; stage A(t+1) rows 0-63,128-191 ----
#pragma unroll
    for (int kk = 0; kk < 2; ++kk) {
      af[0][kk] = ldf(Ar, wr * 128 + 4 * 16 + lr, kk);
      af[1][kk] = ldf(Ar, wr * 128 + 5 * 16 + lr, kk);
    }
    if (st) { stg(Agt, Aw, 0); stg(Agt, Aw, 128); }
    barrier_raw();
    MMA16(2);
    barrier_raw();

    // ---- phase 3: A m6,7 ; stage A(t+1) rows 64-127,192-255 ; boundary wait ----
#pragma unroll
    for (int kk = 0; kk < 2; ++kk) {
      af[0][kk] = ldf(Ar, wr * 128 + 6 * 16 + lr, kk);
      af[1][kk] = ldf(Ar, wr * 128 + 7 * 16 + lr, kk);
    }
    if (st) { stg(Agt, Aw, 64); stg(Agt, Aw, 192); }
    barrier_raw();
    MMA16(3);
    if (st) { VMCNT(2); } else { VMCNT(0); }
    barrier_raw();
  }
#undef MMA16

  // epilogue: bias + scatter to [B,H,S,D] fp16
  const int tsel = col0 >> 10;
  const float* bp = tsel == 0 ? qb : (tsel == 1 ? kb : vb);
  h16* outp = tsel == 0 ? qo : (tsel == 1 ? ko : vo);
#pragma unroll
  for (int n = 0; n < 4; ++n) {
    const int cidx = col0 + wc * 64 + n * 16 + lr;
    const int jj = cidx & 1023;
    const float bv = bp[jj];
    const int hh = jj >> 6, dd = jj & 63;
#pragma unroll
    for (int m = 0; m < 8; ++m) {
#pragma unroll
      for (int j = 0; j < 4; ++j) {
        const int r = row0 + wr * 128 + m * 16 + lg * 4 + j;
        const int bb = r >> 11, ss = r & 2047;
        outp[(((size_t)bb * 16 + hh) * 2048 + ss) * 64 + dd] =
            (h16)(acc[m][n][j] + bv);
      }
    }
  }
}

// ---------------- final projection GEMM (128x128 tile, unchanged) ----------------
__global__ __launch_bounds__(256) void gemm_o(
    const h16* __restrict__ A, const h16* __restrict__ Bw,
    const float* __restrict__ b0, float* __restrict__ Cf, int M, int N, int K) {
  __shared__ __align__(16) h16 Ash[128 * 32];
  __shared__ __align__(16) h16 Bsh[128 * 32];
  const int tid = threadIdx.x;
  const int wave = tid >> 6, lane = tid & 63;
  const int lr = lane & 15, lg = lane >> 4;
  const int wr = wave >> 1, wc = wave & 1;
  const int row0 = blockIdx.x * 128, col0 = blockIdx.y * 128;

  f32x4 acc[4][4] = {};

  const int nk = K >> 5;
  for (int kt = 0; kt < nk; ++kt) {
#pragma unroll
    for (int i = 0; i < 2; ++i) {
      const int grp = wave * 2 + i;
      const int c = grp * 64 + lane;
      const int r = c >> 2, cc = c & 3;
      gl2lds16(A + (size_t)(row0 + r) * K + kt * 32 + cc * 8, &Ash[grp * 512]);
      gl2lds16(Bw + (size_t)(col0 + r) * K + kt * 32 + cc * 8, &Bsh[grp * 512]);
    }
    __syncthreads();
    h8 af[4], bf[4];
#pragma unroll
    for (int m = 0; m < 4; ++m)
      af[m] = *(const h8*)&Ash[(wr * 64 + m * 16 + lr) * 32 + lg * 8];
#pragma unroll
    for (int n = 0; n < 4; ++n)
      bf[n] = *(const h8*)&Bsh[(wc * 64 + n * 16 + lr) * 32 + lg * 8];
#pragma unroll
    for (int m = 0; m < 4; ++m)
#pragma unroll
      for (int n = 0; n < 4; ++n)
        acc[m][n] =
            __builtin_amdgcn_mfma_f32_16x16x32_f16(af[m], bf[n], acc[m][n], 0, 0, 0);
    __syncthreads();
  }

#pragma unroll
  for (int m = 0; m < 4; ++m)
#pragma unroll
    for (int n = 0; n < 4; ++n)
#pragma unroll
      for (int j = 0; j < 4; ++j) {
        const int r = row0 + wr * 64 + m * 16 + lg * 4 + j;
        const int cidx = col0 + wc * 64 + n * 16 + lr;
        Cf[(size_t)r * N + cidx] = acc[m][n][j] + b0[cidx];
      }
}

// ---------------- sliding-window attention (unchanged) ----------------
__global__ __launch_bounds__(256) void swattn(const h16* __restrict__ Q,
                                              const h16* __restrict__ K,
                                              const h16* __restrict__ V,
                                              h16* __restrict__ O) {
  __shared__ __align__(16) h16 Ksh[128 * 72];
  __shared__ __align__(16) h16 Vsh[64 * 136];
  __shared__ __align__(16) h16 Psh[4][16 * 136];

  const int qb0 = blockIdx.x * 64;
  const int bh = blockIdx.y;
  const int b = bh >> 4, h = bh & 15;
  const int tid = threadIdx.x;
  const int wave = tid >> 6, lane = tid & 63;
  const int lr = lane & 15, lg = lane >> 4;

  const h16* Qb = Q + (size_t)bh * 2048 * 64;
  const h16* Kb = K + (size_t)bh * 2048 * 64;
  const h16* Vb = V + (size_t)bh * 2048 * 64;

#pragma unroll
  for (int i = 0; i < 4; ++i) {
    const int c = tid * 4 + i;
    const int row = c >> 3, c8 = c & 7;
    const int t = qb0 - 32 + row;
    h8 kv, vv;
    if (t >= 0 && t < 2048) {
      kv = *(const h8*)&Kb[(size_t)t * 64 + c8 * 8];
      vv = *(const h8*)&Vb[(size_t)t * 64 + c8 * 8];
    } else {
#pragma unroll
      for (int j = 0; j < 8; ++j) { kv[j] = (h16)0.f; vv[j] = (h16)0.f; }
    }
    *(h8*)&Ksh[row * 72 + c8 * 8] = kv;
#pragma unroll
    for (int j = 0; j < 8; ++j) Vsh[(c8 * 8 + j) * 136 + row] = vv[j];
  }
  __syncthreads();

  const int qrow = qb0 + wave * 16 + lr;
  h8 qa[2];
#pragma unroll
  for (int kk = 0; kk < 2; ++kk)
    qa[kk] = *(const h8*)&Qb[(size_t)qrow * 64 + kk * 32 + lg * 8];

  f32x4 sacc[8] = {};
#pragma unroll
  for (int n = 0; n < 8; ++n)
#pragma unroll
    for (int kk = 0; kk < 2; ++kk) {
      h8 kb = *(const h8*)&Ksh[(n * 16 + lr) * 72 + kk * 32 + lg * 8];
      sacc[n] = __builtin_amdgcn_mfma_f32_16x16x32_f16(qa[kk], kb, sacc[n], 0, 0, 0);
    }

  float p[8][4];
#pragma unroll
  for (int j = 0; j < 4; ++j) {
    const int wrow = wave * 16 + lg * 4 + j;
    float mx = -1e30f;
#pragma unroll
    for (int n = 0; n < 8; ++n) {
      const int d = n * 16 + lr - wrow;
      float s = (d < 0 || d > 64) ? -1e30f : sacc[n][j] * 0.125f;
      p[n][j] = s;
      mx = fmaxf(mx, s);
    }
#pragma unroll
    for (int off = 1; off < 16; off <<= 1) mx = fmaxf(mx, __shfl_xor(mx, off, 64));
    float sum = 0.f;
#pragma unroll
    for (int n = 0; n < 8; ++n) {
      const float e = __expf(p[n][j] - mx);
      p[n][j] = e;
      sum += e;
    }
#pragma unroll
    for (int off = 1; off < 16; off <<= 1) sum += __shfl_xor(sum, off, 64);
    const float inv = 1.f / sum;
#pragma unroll
    for (int n = 0; n < 8; ++n) p[n][j] *= inv;
  }

#pragma unroll
  for (int n = 0; n < 8; ++n)
#pragma unroll
    for (int j = 0; j < 4; ++j)
      Psh[wave][(lg * 4 + j) * 136 + n * 16 + lr] = (h16)p[n][j];
  __syncthreads();

  f32x4 oacc[4] = {};
#pragma unroll
  for (int kk = 0; kk < 4; ++kk) {
    h8 pa = *(const h8*)&Psh[wave][lr * 136 + kk * 32 + lg * 8];
#pragma unroll
    for (int n = 0; n < 4; ++n) {
      h8 vb = *(const h8*)&Vsh[(n * 16 + lr) * 136 + kk * 32 + lg * 8];
      oacc[n] = __builtin_amdgcn_mfma_f32_16x16x32_f16(pa, vb, oacc[n], 0, 0, 0);
    }
  }

#pragma unroll
  for (int n = 0; n < 4; ++n)
#pragma unroll
    for (int j = 0; j < 4; ++j) {
      const int s = qb0 + wave * 16 + lg * 4 + j;
      const int d = n * 16 + lr;
      O[((size_t)b * 2048 + s) * 1024 + h * 64 + d] = (h16)oacc[n][j];
    }
}

extern "C" void kernel_launch(void* const* d_in, const int* in_sizes, int n_in,
                              void* d_out, int out_size, void* d_ws, size_t ws_size,
                              hipStream_t stream) {
  const float* hs = (const float*)d_in[0];
  const float* qw = (const float*)d_in[1];
  const float* qb = (const float*)d_in[2];
  const float* kw = (const float*)d_in[3];
  const float* kb = (const float*)d_in[4];
  const float* vw = (const float*)d_in[5];
  const float* vb = (const float*)d_in[6];
  const float* ow = (const float*)d_in[7];
  const float* ob = (const float*)d_in[8];

  const int M = in_sizes[0] / 1024;  // B * S = 4096

  h16* hsH = (h16*)d_ws;
  h16* wqkv = hsH + (size_t)M * 1024;           // 3072 x 1024 (q,k,v stacked)
  h16* woH = wqkv + (size_t)3072 * 1024;        // 1024 x 1024
  h16* qH = woH + (size_t)1024 * 1024;          // [B,H,S,D]
  h16* kH = qH + (size_t)M * 1024;
  h16* vH = kH + (size_t)M * 1024;
  h16* attnH = vH + (size_t)M * 1024;           // [B,S,E]

  const int tot = M * 1024 + 4 * 1048576;
  f2h_all<<<(tot / 8 + 255) / 256, 256, 0, stream>>>(hs, qw, kw, vw, ow, hsH,
                                                     M * 1024);

  const int nbm = M / 256;
  const int nwg = nbm * 12;
  qkv8<<<nwg, 512, 0, stream>>>(hsH, wqkv, qb, kb, vb, qH, kH, vH, nbm, nwg / 8);

  swattn<<<dim3(32, M / 2048 * 16), 256, 0, stream>>>(qH, kH, vH, attnH);

  gemm_o<<<dim3(M / 128, 8), 256, 0, stream>>>(attnH, woH, ob, (float*)d_out, M,
                                               1024, 1024);
}